// Round 6
// baseline (219.010 us; speedup 1.0000x reference)
//
#include <hip/hip_runtime.h>
#include <math.h>

#define TPB 256
#define CPT 8                          // int4-label chunks per thread
#define CHUNKS_PER_BLOCK (TPB * CPT)
#define TPB_F 256

typedef float fx4 __attribute__((ext_vector_type(4)));
typedef int   ix4 __attribute__((ext_vector_type(4)));

// ws layout: double ce_part[nparts] ; unsigned long long cnt_part[nparts]
// No zero-init needed: every block writes its slot unconditionally each launch.

__device__ __forceinline__ void proc(float o0, float o1, int l,
                                     float& ce, unsigned long long& cnt) {
    // d = o0-o1; pred = (d<0); ce += relu(l? d : -d) + log(1+exp(-|d|))
    const float d = o0 - o1;
    ce += fmaxf(l ? d : -d, 0.0f) + __logf(1.0f + __expf(-fabsf(d)));
    cnt += 1ull << ((((l << 1) | (d < 0.0f ? 1 : 0))) << 4);  // field = label*2+pred
}

__global__ __launch_bounds__(TPB) void detloss_main(
    const fx4* __restrict__ out4,   // outputs as float4 (2 elements each)
    const ix4* __restrict__ lab4,   // labels as int4 (4 elements each)
    double* __restrict__ ce_part,
    unsigned long long* __restrict__ cnt_part,
    int nchunks)
{
    float ce = 0.0f;
    unsigned long long cnt = 0ull;   // 4 x 16-bit fields (<=32 per field per thread)
    const int tid  = threadIdx.x;
    const int base = blockIdx.x * CHUNKS_PER_BLOCK + tid;

    if (base + (CPT - 1) * TPB < nchunks) {
        // fast path: all 24 loads issued up front, nontemporal (read-once stream)
        ix4 lb[CPT];
        fx4 a[CPT], b[CPT];
        #pragma unroll
        for (int k = 0; k < CPT; ++k)
            lb[k] = __builtin_nontemporal_load(lab4 + base + k * TPB);
        #pragma unroll
        for (int k = 0; k < CPT; ++k) {
            a[k] = __builtin_nontemporal_load(out4 + 2 * (base + k * TPB));
            b[k] = __builtin_nontemporal_load(out4 + 2 * (base + k * TPB) + 1);
        }
        #pragma unroll
        for (int k = 0; k < CPT; ++k) {
            proc(a[k].x, a[k].y, lb[k].x, ce, cnt);
            proc(a[k].z, a[k].w, lb[k].y, ce, cnt);
            proc(b[k].x, b[k].y, lb[k].z, ce, cnt);
            proc(b[k].z, b[k].w, lb[k].w, ce, cnt);
        }
    } else {
        // tail blocks (unused for B = 2^24): per-chunk guards
        #pragma unroll
        for (int k = 0; k < CPT; ++k) {
            const int g = base + k * TPB;
            if (g < nchunks) {
                const ix4 lb = lab4[g];
                const fx4 a = out4[2*g], b = out4[2*g+1];
                proc(a.x,a.y,lb.x,ce,cnt); proc(a.z,a.w,lb.y,ce,cnt);
                proc(b.x,b.y,lb.z,ce,cnt); proc(b.z,b.w,lb.w,ce,cnt);
            }
        }
    }

    // wave (64-lane) shuffle reduction
    #pragma unroll
    for (int off = 32; off > 0; off >>= 1) {
        ce  += __shfl_down(ce, off);
        cnt += __shfl_down(cnt, off);
    }

    __shared__ float              s_ce[TPB / 64];
    __shared__ unsigned long long s_cnt[TPB / 64];
    const int wave = tid >> 6;
    const int lane = tid & 63;
    if (lane == 0) { s_ce[wave] = ce; s_cnt[wave] = cnt; }
    __syncthreads();

    if (tid == 0) {
        float bce = 0.0f;
        unsigned long long bc = 0ull;   // block totals <= 8192/field, fits 16 bits
        #pragma unroll
        for (int w = 0; w < TPB / 64; ++w) { bce += s_ce[w]; bc += s_cnt[w]; }
        ce_part[blockIdx.x]  = (double)bce;   // unique slots — no atomics
        cnt_part[blockIdx.x] = bc;
    }
}

__global__ __launch_bounds__(TPB_F) void detloss_final(
    const double* __restrict__ ce_part,
    const unsigned long long* __restrict__ cnt_part,
    float* __restrict__ out, int B, int nparts)
{
    double ce = 0.0;
    // unpack BEFORE cross-block summation (16-bit fields would overflow)
    unsigned int q0 = 0, q1 = 0, q2 = 0, q3 = 0;
    for (int s = threadIdx.x; s < nparts; s += TPB_F) {
        ce += ce_part[s];
        const unsigned long long c = cnt_part[s];
        q0 += (unsigned int)( c        & 0xffffull);  // TN
        q1 += (unsigned int)((c >> 16) & 0xffffull);  // FP
        q2 += (unsigned int)((c >> 32) & 0xffffull);  // FN
        q3 += (unsigned int)( c >> 48);               // TP
    }

    #pragma unroll
    for (int off = 32; off > 0; off >>= 1) {
        ce += __shfl_down(ce, off);
        q0 += __shfl_down(q0, off);
        q1 += __shfl_down(q1, off);
        q2 += __shfl_down(q2, off);
        q3 += __shfl_down(q3, off);
    }

    __shared__ double       s_ce[TPB_F / 64];
    __shared__ unsigned int s_q[4][TPB_F / 64];
    const int wave = threadIdx.x >> 6;
    const int lane = threadIdx.x & 63;
    if (lane == 0) {
        s_ce[wave] = ce;
        s_q[0][wave] = q0; s_q[1][wave] = q1; s_q[2][wave] = q2; s_q[3][wave] = q3;
    }
    __syncthreads();

    if (threadIdx.x == 0) {
        double ceT = 0.0;
        unsigned int TNu = 0, FPu = 0, FNu = 0, TPu = 0;
        #pragma unroll
        for (int w = 0; w < TPB_F / 64; ++w) {
            ceT += s_ce[w];
            TNu += s_q[0][w]; FPu += s_q[1][w]; FNu += s_q[2][w]; TPu += s_q[3][w];
        }
        const double TN = (double)TNu, FP = (double)FPu,
                     FN = (double)FNu, TP = (double)TPu;
        const double invB = 1.0 / (double)B;
        const bool nonzero = (TP > 0.0) && (TN > 0.0) && (FP > 0.0) && (FN > 0.0);
        const double ratio = (TP / fmax(TP + FN, 1.0)) * (FP / fmax(FP + TN, 1.0));
        const double coeff = nonzero ? (-0.5 * log(sqrt(fmax(ratio, 1e-30)))) : 0.5;
        // N_CLASSES=2: M[pred,label]==1 only when pred=0 & label=1 => sum(CS) == FN
        out[0] = (float)(ceT * invB + coeff * FN * invB);
    }
}

extern "C" void kernel_launch(void* const* d_in, const int* in_sizes, int n_in,
                              void* d_out, int out_size, void* d_ws, size_t ws_size,
                              hipStream_t stream) {
    const float* outputs = (const float*)d_in[0];
    const int*   labels  = (const int*)d_in[1];
    const int B = in_sizes[1];

    const int nchunks = B / 4;                                   // B = 2^24
    const int nparts  = (nchunks + CHUNKS_PER_BLOCK - 1) / CHUNKS_PER_BLOCK;  // 2048

    double*             ce_part  = (double*)d_ws;
    unsigned long long* cnt_part = (unsigned long long*)((char*)d_ws
                                                         + (size_t)nparts * sizeof(double));

    detloss_main<<<nparts, TPB, 0, stream>>>(
        (const fx4*)outputs, (const ix4*)labels, ce_part, cnt_part, nchunks);
    detloss_final<<<1, TPB_F, 0, stream>>>(ce_part, cnt_part, (float*)d_out, B, nparts);
}